// Round 1
// baseline (39533.707 us; speedup 1.0000x reference)
//
#include <hip/hip_runtime.h>
#include <hip/hip_cooperative_groups.h>

namespace cg = cooperative_groups;

#define B_SZ   64
#define S_LEN  512
#define N_IN   128
#define HID    1024
#define N_OUT  128

// Grid: 256 blocks x 256 threads. One thread computes one h[b][j] per step.
//   b = tid & 63  (wave lanes span batches -> W row loads are wave-broadcast)
//   j = bid*4 + (tid>>6)
// ws layout (floats): hbuf0[64*1024] | hbuf1[64*1024] | mlp[64*1024]  (768 KB)
__global__ void __launch_bounds__(256) rnn_fused(
    const float* __restrict__ x,    const float* __restrict__ h0,
    const float* __restrict__ W_ih, const float* __restrict__ b_ih,
    const float* __restrict__ W_hh, const float* __restrict__ b_hh,
    const float* __restrict__ W1,   const float* __restrict__ b1,
    const float* __restrict__ W2,   const float* __restrict__ b2,
    float* __restrict__ out, float* __restrict__ ws)
{
    cg::grid_group grid = cg::this_grid();
    const int tid = threadIdx.x;
    const int bid = blockIdx.x;
    const int b = tid & 63;
    const int j = bid * 4 + (tid >> 6);

    float* hbuf0 = ws;                  // [B][H]
    float* hbuf1 = ws + B_SZ * HID;     // [B][H]
    float* mlp   = ws + 2 * B_SZ * HID; // [B][H]

    // init hbuf0 = h0 (65536 elements, 65536 threads)
    {
        const int g = bid * 256 + tid;
        hbuf0[g] = h0[g];
    }

    const float bias = b_ih[j] + b_hh[j];
    const float4* __restrict__ wih_row = reinterpret_cast<const float4*>(W_ih + (size_t)j * N_IN);
    const float4* __restrict__ whh_row = reinterpret_cast<const float4*>(W_hh + (size_t)j * HID);

    grid.sync();

    float* cur = hbuf0;
    float* nxt = hbuf1;
    for (int t = 0; t < S_LEN; ++t) {
        float acc = bias;
        // x_t @ W_ih^T  (on-the-fly input projection)
        const float4* __restrict__ xrow =
            reinterpret_cast<const float4*>(x + ((size_t)b * S_LEN + t) * N_IN);
        #pragma unroll 8
        for (int k = 0; k < N_IN / 4; ++k) {
            const float4 xv = xrow[k];
            const float4 wv = wih_row[k];
            acc += xv.x * wv.x + xv.y * wv.y + xv.z * wv.z + xv.w * wv.w;
        }
        // h_{t-1} @ W_hh^T
        const float4* __restrict__ hrow =
            reinterpret_cast<const float4*>(cur + (size_t)b * HID);
        #pragma unroll 8
        for (int k = 0; k < HID / 4; ++k) {
            const float4 hv = hrow[k];
            const float4 wv = whh_row[k];
            acc += hv.x * wv.x + hv.y * wv.y + hv.z * wv.z + hv.w * wv.w;
        }
        nxt[(size_t)b * HID + j] = tanhf(acc);
        float* tmp = cur; cur = nxt; nxt = tmp;
        grid.sync();   // h_t fully visible before anyone starts step t+1
    }
    // cur == h_last here (writes published by the final grid.sync in the loop)

    // h_last -> out[8192 ..]
    {
        const int g = bid * 256 + tid;
        out[B_SZ * N_OUT + g] = cur[g];
    }

    // mlp[b][i] = relu(h_last[b] . W1[i] + b1[i])  (one per thread, i == j)
    {
        const float4* __restrict__ hrow  = reinterpret_cast<const float4*>(cur + (size_t)b * HID);
        const float4* __restrict__ w1row = reinterpret_cast<const float4*>(W1 + (size_t)j * HID);
        float acc = b1[j];
        #pragma unroll 8
        for (int k = 0; k < HID / 4; ++k) {
            const float4 hv = hrow[k];
            const float4 wv = w1row[k];
            acc += hv.x * wv.x + hv.y * wv.y + hv.z * wv.z + hv.w * wv.w;
        }
        mlp[(size_t)b * HID + j] = fmaxf(acc, 0.0f);
    }
    grid.sync();

    // out[b][o] = mlp[b] . W2[o] + b2[o]   (8192 outputs -> blocks 0..31)
    if (bid < 32) {
        const int g  = bid * 256 + tid;   // 0..8191
        const int bb = g >> 7;            // batch
        const int o  = g & 127;           // output channel
        const float4* __restrict__ mrow  = reinterpret_cast<const float4*>(mlp + (size_t)bb * HID);
        const float4* __restrict__ w2row = reinterpret_cast<const float4*>(W2 + (size_t)o * HID);
        float acc = b2[o];
        #pragma unroll 8
        for (int k = 0; k < HID / 4; ++k) {
            const float4 mv = mrow[k];
            const float4 wv = w2row[k];
            acc += mv.x * wv.x + mv.y * wv.y + mv.z * wv.z + mv.w * wv.w;
        }
        out[g] = acc;
    }
}

extern "C" void kernel_launch(void* const* d_in, const int* in_sizes, int n_in,
                              void* d_out, int out_size, void* d_ws, size_t ws_size,
                              hipStream_t stream) {
    const float* x    = (const float*)d_in[0];
    const float* h0   = (const float*)d_in[1];
    const float* W_ih = (const float*)d_in[2];
    const float* b_ih = (const float*)d_in[3];
    const float* W_hh = (const float*)d_in[4];
    const float* b_hh = (const float*)d_in[5];
    const float* W1   = (const float*)d_in[6];
    const float* b1   = (const float*)d_in[7];
    const float* W2   = (const float*)d_in[8];
    const float* b2   = (const float*)d_in[9];
    float* out = (float*)d_out;
    float* ws  = (float*)d_ws;

    void* args[] = {&x, &h0, &W_ih, &b_ih, &W_hh, &b_hh, &W1, &b1, &W2, &b2, &out, &ws};
    hipLaunchCooperativeKernel(reinterpret_cast<void*>(rnn_fused),
                               dim3(256), dim3(256), args, 0, stream);
}

// Round 2
// 11624.381 us; speedup vs baseline: 3.4009x; 3.4009x over previous
//
#include <hip/hip_runtime.h>
#include <hip/hip_cooperative_groups.h>

namespace cg = cooperative_groups;

#define HID   1024
#define NIN   128
#define BSZ   64
#define SLEN  512
#define KTOT  1152   // 1024 (W_hh) + 128 (W_ih)

typedef short          bf16x8 __attribute__((ext_vector_type(8)));
typedef unsigned short us4    __attribute__((ext_vector_type(4)));
typedef float          f32x4  __attribute__((ext_vector_type(4)));

__device__ __forceinline__ unsigned short rne_bf16(float f) {
    unsigned int u = __builtin_bit_cast(unsigned int, f);
    u += 0x7FFFu + ((u >> 16) & 1u);
    return (unsigned short)(u >> 16);
}
__device__ __forceinline__ float bf2f(unsigned short h) {
    unsigned int u = ((unsigned int)h) << 16;
    return __builtin_bit_cast(float, u);
}

// ws layout in ushort units:
//   Whi[1024*1152] | Wlo[1024*1152] | hh0[64K] | hl0[64K] | hh1[64K] | hl1[64K]
// then float units:
//   hfp[64K] | mlp[64K]
#define OFF_WLO (1024 * KTOT)
#define OFF_HH0 (2 * 1024 * KTOT)
#define OFF_HL0 (OFF_HH0 + 65536)
#define OFF_HH1 (OFF_HH0 + 2 * 65536)
#define OFF_HL1 (OFF_HH0 + 3 * 65536)
#define OFF_F32 (OFF_HH0 + 4 * 65536)

// One-time: split W = [W_hh | W_ih] into bf16 hi/lo, and h0 into hi/lo.
__global__ void __launch_bounds__(256) prep(
    const float* __restrict__ W_ih, const float* __restrict__ W_hh,
    const float* __restrict__ h0, unsigned short* __restrict__ wsu)
{
    const int g = blockIdx.x * 256 + threadIdx.x;
    if (g < 1024 * KTOT) {
        const int j = g / KTOT;
        const int k = g - j * KTOT;
        const float v = (k < HID) ? W_hh[j * HID + k] : W_ih[j * NIN + (k - HID)];
        const unsigned short hi = rne_bf16(v);
        wsu[g] = hi;
        wsu[OFF_WLO + g] = rne_bf16(v - bf2f(hi));
    } else {
        const int e = g - 1024 * KTOT;   // 0..65535
        const float v = h0[e];
        const unsigned short hi = rne_bf16(v);
        wsu[OFF_HH0 + e] = hi;
        wsu[OFF_HL0 + e] = rne_bf16(v - bf2f(hi));
    }
}

// Cooperative kernel: 64 blocks x 256 threads.
// Block bid owns j-tile [bid*16, bid*16+16). Waves split K=1152 as chunks
// (s*4 + wave)*32, s=0..8; chunk 32..35 (s==8) is the x-projection columns.
__global__ void __launch_bounds__(256, 1) rnn_mfma(
    const float* __restrict__ x,
    const float* __restrict__ b_ih, const float* __restrict__ b_hh,
    const float* __restrict__ W1,   const float* __restrict__ b1,
    const float* __restrict__ W2,   const float* __restrict__ b2,
    float* __restrict__ out, unsigned short* __restrict__ wsu)
{
    cg::grid_group grid = cg::this_grid();
    const int tid  = threadIdx.x, bid = blockIdx.x;
    const int wave = tid >> 6,    lane = tid & 63;
    const int lr   = lane & 15,   lg   = lane >> 4;

    const unsigned short* Whi = wsu;
    const unsigned short* Wlo = wsu + OFF_WLO;
    unsigned short* hhc = wsu + OFF_HH0;   // current h (hi)
    unsigned short* hlc = wsu + OFF_HL0;   // current h (lo)
    unsigned short* hhn = wsu + OFF_HH1;   // next h (hi)
    unsigned short* hln = wsu + OFF_HL1;   // next h (lo)
    float* hfp = (float*)(wsu + OFF_F32);  // fp32 h_last
    float* mlp = hfp + 65536;

    // Preload this lane's W fragments for all 9 k-steps (loop-invariant).
    const int j = bid * 16 + lr;
    bf16x8 wh[9], wl[9];
    #pragma unroll
    for (int s = 0; s < 9; ++s) {
        const int kb = (s * 4 + wave) * 32 + lg * 8;
        wh[s] = *(const bf16x8*)(Whi + j * KTOT + kb);
        wl[s] = *(const bf16x8*)(Wlo + j * KTOT + kb);
    }

    // Epilogue mapping: thread -> (batch row em, 4 consecutive j at jg0).
    const int em  = tid >> 2;            // 0..63
    const int ejq = tid & 3;
    const int jg0 = bid * 16 + ejq * 4;
    float bias[4];
    #pragma unroll
    for (int r = 0; r < 4; ++r) bias[r] = b_ih[jg0 + r] + b_hh[jg0 + r];

    __shared__ float red[4][64][17];
    const f32x4 zero = {0.0f, 0.0f, 0.0f, 0.0f};

    for (int t = 0; t < SLEN; ++t) {
        f32x4 acc[4];
        #pragma unroll
        for (int mt = 0; mt < 4; ++mt) acc[mt] = zero;

        #pragma unroll
        for (int s = 0; s < 9; ++s) {
            const int kb = (s * 4 + wave) * 32;
            if (s < 8) {
                #pragma unroll
                for (int mt = 0; mt < 4; ++mt) {
                    const int b = mt * 16 + lr;
                    const bf16x8 ah = *(const bf16x8*)(hhc + b * HID + kb + lg * 8);
                    const bf16x8 al = *(const bf16x8*)(hlc + b * HID + kb + lg * 8);
                    acc[mt] = __builtin_amdgcn_mfma_f32_16x16x32_bf16(ah, wh[s], acc[mt], 0, 0, 0);
                    acc[mt] = __builtin_amdgcn_mfma_f32_16x16x32_bf16(ah, wl[s], acc[mt], 0, 0, 0);
                    acc[mt] = __builtin_amdgcn_mfma_f32_16x16x32_bf16(al, wh[s], acc[mt], 0, 0, 0);
                }
            } else {
                // x-projection columns: c = wave*32 + lg*8, on-the-fly hi/lo split
                const int c = wave * 32 + lg * 8;
                #pragma unroll
                for (int mt = 0; mt < 4; ++mt) {
                    const int b = mt * 16 + lr;
                    const float* xp = x + ((size_t)b * SLEN + t) * NIN + c;
                    const f32x4 x0 = *(const f32x4*)xp;
                    const f32x4 x1 = *(const f32x4*)(xp + 4);
                    bf16x8 ah, al;
                    #pragma unroll
                    for (int e = 0; e < 4; ++e) {
                        const unsigned short h0b = rne_bf16(x0[e]);
                        ah[e] = (short)h0b;
                        al[e] = (short)rne_bf16(x0[e] - bf2f(h0b));
                        const unsigned short h1b = rne_bf16(x1[e]);
                        ah[4 + e] = (short)h1b;
                        al[4 + e] = (short)rne_bf16(x1[e] - bf2f(h1b));
                    }
                    acc[mt] = __builtin_amdgcn_mfma_f32_16x16x32_bf16(ah, wh[s], acc[mt], 0, 0, 0);
                    acc[mt] = __builtin_amdgcn_mfma_f32_16x16x32_bf16(ah, wl[s], acc[mt], 0, 0, 0);
                    acc[mt] = __builtin_amdgcn_mfma_f32_16x16x32_bf16(al, wh[s], acc[mt], 0, 0, 0);
                }
            }
        }

        // Stash per-wave partials: C[m][n] at m=(lane>>4)*4+reg, n=lane&15 (m89)
        #pragma unroll
        for (int mt = 0; mt < 4; ++mt)
            #pragma unroll
            for (int r = 0; r < 4; ++r)
                red[wave][mt * 16 + lg * 4 + r][lr] = acc[mt][r];
        __syncthreads();

        // Reduce 4 K-partials, add bias, tanh, split to bf16 hi/lo.
        us4 hv, lv; f32x4 fv;
        #pragma unroll
        for (int r = 0; r < 4; ++r) {
            const int jl = ejq * 4 + r;
            float s = red[0][em][jl] + red[1][em][jl] + red[2][em][jl] + red[3][em][jl]
                    + bias[r];
            const float v = tanhf(s);
            const unsigned short hb = rne_bf16(v);
            hv[r] = hb;
            lv[r] = rne_bf16(v - bf2f(hb));
            fv[r] = v;
        }
        *(us4*)(hhn + em * HID + jg0) = hv;
        *(us4*)(hln + em * HID + jg0) = lv;
        if (t == SLEN - 1) *(f32x4*)(hfp + em * HID + jg0) = fv;

        unsigned short* tp;
        tp = hhc; hhc = hhn; hhn = tp;
        tp = hlc; hlc = hln; hln = tp;
        grid.sync();   // publish h_t (incl. block-local reuse of `red`)
    }

    // h_last -> out[8192..]
    {
        const int g = bid * 256 + tid;            // 0..16383, x4 floats
        ((f32x4*)(out + BSZ * 128))[g] = ((const f32x4*)hfp)[g];
    }

    // mlp[b][j] = relu(h_last[b] . W1[j] + b1[j]); thread: j fixed, 4 batches
    {
        const int jj = bid * 16 + (tid >> 4);     // 0..1023
        const int bq = tid & 15;
        const float* w1r = W1 + (size_t)jj * HID;
        float a[4] = {0.f, 0.f, 0.f, 0.f};
        for (int k4 = 0; k4 < HID / 4; ++k4) {
            const f32x4 wv = ((const f32x4*)w1r)[k4];
            #pragma unroll
            for (int i = 0; i < 4; ++i) {
                const f32x4 hv = ((const f32x4*)(hfp + (size_t)(bq * 4 + i) * HID))[k4];
                a[i] += wv[0] * hv[0] + wv[1] * hv[1] + wv[2] * hv[2] + wv[3] * hv[3];
            }
        }
        const float bj = b1[jj];
        #pragma unroll
        for (int i = 0; i < 4; ++i)
            mlp[(size_t)(bq * 4 + i) * HID + jj] = fmaxf(a[i] + bj, 0.0f);
    }
    grid.sync();

    // out[b][o] = mlp[b] . W2[o] + b2[o]
    if (bid < 32) {
        const int g = bid * 256 + tid;            // 0..8191
        const int o = g >> 6, b = g & 63;
        const float* w2r = W2 + (size_t)o * HID;
        const float* mr  = mlp + (size_t)b * HID;
        float a = 0.f;
        for (int k4 = 0; k4 < HID / 4; ++k4) {
            const f32x4 wv = ((const f32x4*)w2r)[k4];
            const f32x4 mv = ((const f32x4*)mr)[k4];
            a += wv[0] * mv[0] + wv[1] * mv[1] + wv[2] * mv[2] + wv[3] * mv[3];
        }
        out[b * 128 + o] = a + b2[o];
    }
}

extern "C" void kernel_launch(void* const* d_in, const int* in_sizes, int n_in,
                              void* d_out, int out_size, void* d_ws, size_t ws_size,
                              hipStream_t stream) {
    const float* x    = (const float*)d_in[0];
    const float* h0   = (const float*)d_in[1];
    const float* W_ih = (const float*)d_in[2];
    const float* b_ih = (const float*)d_in[3];
    const float* W_hh = (const float*)d_in[4];
    const float* b_hh = (const float*)d_in[5];
    const float* W1   = (const float*)d_in[6];
    const float* b1   = (const float*)d_in[7];
    const float* W2   = (const float*)d_in[8];
    const float* b2   = (const float*)d_in[9];
    float* out = (float*)d_out;
    unsigned short* wsu = (unsigned short*)d_ws;

    // prep: 1024*1152 W elements + 65536 h0 elements
    const int nprep = 1024 * KTOT + 65536;
    prep<<<nprep / 256, 256, 0, stream>>>(W_ih, W_hh, h0, wsu);

    void* args[] = {&x, &b_ih, &b_hh, &W1, &b1, &W2, &b2, &out, &wsu};
    hipLaunchCooperativeKernel(reinterpret_cast<void*>(rnn_mfma),
                               dim3(64), dim3(256), args, 0, stream);
}

// Round 3
// 6759.627 us; speedup vs baseline: 5.8485x; 1.7197x over previous
//
#include <hip/hip_runtime.h>
#include <hip/hip_cooperative_groups.h>

namespace cg = cooperative_groups;

#define HID   1024
#define NIN   128
#define BSZ   64
#define SLEN  512
#define KTOT  1152   // 1024 (W_hh) + 128 (W_ih)
#define NBLK  64
#define NOUT  128
#define WP    1176   // padded W row length in ushorts (16B-aligned rows, ~2-way banks)

typedef short          bf16x8 __attribute__((ext_vector_type(8)));
typedef unsigned short us8    __attribute__((ext_vector_type(8)));
typedef float          f32x4  __attribute__((ext_vector_type(4)));

__device__ __forceinline__ unsigned short rne_bf16(float f) {
    unsigned int u = __builtin_bit_cast(unsigned int, f);
    u += 0x7FFFu + ((u >> 16) & 1u);
    return (unsigned short)(u >> 16);
}
__device__ __forceinline__ float bf2f(unsigned short h) {
    unsigned int u = ((unsigned int)h) << 16;
    return __builtin_bit_cast(float, u);
}

// ws layout (ushort units):
//  Whi[1024*1152] | Wlo[1024*1152] | hh0[64K] | hl0[64K] | hh1[64K] | hl1[64K]
//  | hfp[64K floats] | mlp[64K floats] | doneW[513]+doneM (uints)
#define OFF_WLO (1024 * KTOT)
#define OFF_HH0 (2 * 1024 * KTOT)
#define OFF_HL0 (OFF_HH0 + 65536)
#define OFF_HH1 (OFF_HH0 + 2 * 65536)
#define OFF_HL1 (OFF_HH0 + 3 * 65536)
#define OFF_F32 (OFF_HH0 + 4 * 65536)
#define OFF_CNT (OFF_F32 + 4 * 65536)

__global__ void __launch_bounds__(256) prep(
    const float* __restrict__ W_ih, const float* __restrict__ W_hh,
    const float* __restrict__ h0, unsigned short* __restrict__ wsu)
{
    const int g = blockIdx.x * 256 + threadIdx.x;
    if (g < SLEN + 2) ((unsigned*)(wsu + OFF_CNT))[g] = 0u;   // doneW[0..512], doneM
    if (g < 1024 * KTOT) {
        const int j = g / KTOT;
        const int k = g - j * KTOT;
        const float v = (k < HID) ? W_hh[j * HID + k] : W_ih[j * NIN + (k - HID)];
        const unsigned short hi = rne_bf16(v);
        wsu[g] = hi;
        wsu[OFF_WLO + g] = rne_bf16(v - bf2f(hi));
    } else if (g < 1024 * KTOT + 65536) {
        const int e = g - 1024 * KTOT;
        const float v = h0[e];
        const unsigned short hi = rne_bf16(v);
        wsu[OFF_HH0 + e] = hi;
        wsu[OFF_HL0 + e] = rne_bf16(v - bf2f(hi));
    }
}

// 64 blocks x 512 threads (8 waves: kc = wave&3 K-chunk, mh = wave>>2 M-half).
// Block owns j-tile [bid*16, bid*16+16). W slice lives in LDS. h in global ws
// (ping-pong), published per step via doneW[t] counters (agent-scope).
__global__ void __launch_bounds__(512, 2) rnn_mfma(
    const float* __restrict__ x,
    const float* __restrict__ b_ih, const float* __restrict__ b_hh,
    const float* __restrict__ W1,   const float* __restrict__ b1,
    const float* __restrict__ W2,   const float* __restrict__ b2,
    float* __restrict__ out, unsigned short* __restrict__ wsu)
{
    const int tid  = threadIdx.x, bid = blockIdx.x;
    const int lane = tid & 63, wave = tid >> 6;
    const int lr = lane & 15, lg = lane >> 4;
    const int kc = wave & 3, mh = wave >> 2;

    const unsigned short* __restrict__ Whi = wsu;
    const unsigned short* __restrict__ Wlo = wsu + OFF_WLO;
    unsigned short* hh0 = wsu + OFF_HH0;
    unsigned short* hl0 = wsu + OFF_HL0;
    unsigned short* hh1 = wsu + OFF_HH1;
    unsigned short* hl1 = wsu + OFF_HL1;
    float* hfp = (float*)(wsu + OFF_F32);
    float* mlp = hfp + 65536;
    unsigned* doneW = (unsigned*)(wsu + OFF_CNT);   // indexed by t (1..512)
    unsigned* doneM = doneW + (SLEN + 1);

    __shared__ unsigned short sW[2][16][WP];   // [hi/lo][j-local][k padded]
    __shared__ float red[4][64][17];           // [kc][batch][j-local]

    // ---- stage W slice (hi+lo) into LDS ----
    for (int e = tid; e < 16 * (KTOT / 8); e += 512) {
        const int r = e / (KTOT / 8), c = e - r * (KTOT / 8);
        *(us8*)&sW[0][r][c * 8] = *(const us8*)(Whi + (size_t)(bid * 16 + r) * KTOT + c * 8);
        *(us8*)&sW[1][r][c * 8] = *(const us8*)(Wlo + (size_t)(bid * 16 + r) * KTOT + c * 8);
    }
    const int jl = tid & 15, b0 = tid >> 4;    // reduce-stage mapping (b0: 0..31)
    const float bias = b_ih[bid * 16 + jl] + b_hh[bid * 16 + jl];
    __syncthreads();

    for (int t = 1; t <= SLEN; ++t) {
        const unsigned short* hh = ((t - 1) & 1) ? hh1 : hh0;
        const unsigned short* hl = ((t - 1) & 1) ? hl1 : hl0;
        unsigned short* hhn = (t & 1) ? hh1 : hh0;
        unsigned short* hln = (t & 1) ? hl1 : hl0;

        if (t > 1) {   // wait until all blocks published h_{t-1}
            if (tid == 0) {
                while (__hip_atomic_load(doneW + (t - 1), __ATOMIC_RELAXED,
                                         __HIP_MEMORY_SCOPE_AGENT) < (unsigned)NBLK)
                    __builtin_amdgcn_s_sleep(2);
                __builtin_amdgcn_fence(__ATOMIC_ACQUIRE, "agent");
            }
            __syncthreads();
        }

        // ---- A fragments: 2 M-tiles x (8 h-ksteps + 1 x-kstep), hi+lo ----
        bf16x8 ahh[2][9], ahl[2][9];
        #pragma unroll
        for (int m = 0; m < 2; ++m) {
            const int brow = (mh * 2 + m) * 16 + lr;
            const unsigned short* hhp = hh + brow * HID + kc * 256 + lg * 8;
            const unsigned short* hlp = hl + brow * HID + kc * 256 + lg * 8;
            #pragma unroll
            for (int ks = 0; ks < 8; ++ks) {
                ahh[m][ks] = *(const bf16x8*)(hhp + ks * 32);
                ahl[m][ks] = *(const bf16x8*)(hlp + ks * 32);
            }
            const float* xp = x + ((size_t)brow * SLEN + (t - 1)) * NIN + kc * 32 + lg * 8;
            const f32x4 x0 = *(const f32x4*)xp;
            const f32x4 x1 = *(const f32x4*)(xp + 4);
            bf16x8 xh, xl;
            #pragma unroll
            for (int e = 0; e < 4; ++e) {
                const unsigned short h0b = rne_bf16(x0[e]);
                xh[e] = (short)h0b;
                xl[e] = (short)rne_bf16(x0[e] - bf2f(h0b));
                const unsigned short h1b = rne_bf16(x1[e]);
                xh[4 + e] = (short)h1b;
                xl[4 + e] = (short)rne_bf16(x1[e] - bf2f(h1b));
            }
            ahh[m][8] = xh; ahl[m][8] = xl;
        }

        f32x4 acc0 = {0.f,0.f,0.f,0.f}, acc1 = {0.f,0.f,0.f,0.f};
        #pragma unroll
        for (int ks = 0; ks < 9; ++ks) {
            const int wc = (ks < 8) ? (kc * 256 + ks * 32 + lg * 8)
                                    : (1024 + kc * 32 + lg * 8);
            const bf16x8 wh = *(const bf16x8*)&sW[0][lr][wc];
            const bf16x8 wl = *(const bf16x8*)&sW[1][lr][wc];
            acc0 = __builtin_amdgcn_mfma_f32_16x16x32_bf16(ahh[0][ks], wh, acc0, 0, 0, 0);
            acc0 = __builtin_amdgcn_mfma_f32_16x16x32_bf16(ahh[0][ks], wl, acc0, 0, 0, 0);
            acc0 = __builtin_amdgcn_mfma_f32_16x16x32_bf16(ahl[0][ks], wh, acc0, 0, 0, 0);
            acc1 = __builtin_amdgcn_mfma_f32_16x16x32_bf16(ahh[1][ks], wh, acc1, 0, 0, 0);
            acc1 = __builtin_amdgcn_mfma_f32_16x16x32_bf16(ahh[1][ks], wl, acc1, 0, 0, 0);
            acc1 = __builtin_amdgcn_mfma_f32_16x16x32_bf16(ahl[1][ks], wh, acc1, 0, 0, 0);
        }

        // ---- stash partials: row = mtile*16 + lg*4 + r, col = lr (m89 layout) ----
        #pragma unroll
        for (int r = 0; r < 4; ++r) {
            red[kc][(mh * 2 + 0) * 16 + lg * 4 + r][lr] = acc0[r];
            red[kc][(mh * 2 + 1) * 16 + lg * 4 + r][lr] = acc1[r];
        }
        __syncthreads();   // SYNC1: partials visible

        // ---- reduce 4 K-chunks + bias, tanh, write h_t slice ----
        #pragma unroll
        for (int half = 0; half < 2; ++half) {
            const int b = b0 + half * 32;
            const float s = red[0][b][jl] + red[1][b][jl] + red[2][b][jl]
                          + red[3][b][jl] + bias;
            const float v = tanhf(s);
            const unsigned short hb = rne_bf16(v);
            hhn[b * HID + bid * 16 + jl] = hb;
            hln[b * HID + bid * 16 + jl] = rne_bf16(v - bf2f(hb));
            if (t == SLEN) {
                hfp[b * HID + bid * 16 + jl] = v;
                out[BSZ * NOUT + b * HID + bid * 16 + jl] = v;
            }
        }
        __syncthreads();   // SYNC2: all h stores drained (vmcnt0) before signal
        if (tid == 0) {
            __builtin_amdgcn_fence(__ATOMIC_RELEASE, "agent");
            __hip_atomic_fetch_add(doneW + t, 1u, __ATOMIC_RELAXED,
                                   __HIP_MEMORY_SCOPE_AGENT);
        }
    }

    // ---- head: wait for full h_last ----
    if (tid == 0) {
        while (__hip_atomic_load(doneW + SLEN, __ATOMIC_RELAXED,
                                 __HIP_MEMORY_SCOPE_AGENT) < (unsigned)NBLK)
            __builtin_amdgcn_s_sleep(2);
        __builtin_amdgcn_fence(__ATOMIC_ACQUIRE, "agent");
    }
    __syncthreads();

    // mlp[b][j] = relu(h_last[b] . W1[j] + b1[j]); j = bid*16+jl, b = b0, b0+32
    {
        const int j = bid * 16 + jl;
        const f32x4* w1r = (const f32x4*)(W1 + (size_t)j * HID);
        const f32x4* h0r = (const f32x4*)(hfp + (size_t)b0 * HID);
        const f32x4* h1r = (const f32x4*)(hfp + (size_t)(b0 + 32) * HID);
        float a0 = 0.f, a1 = 0.f;
        for (int k4 = 0; k4 < HID / 4; ++k4) {
            const f32x4 wv = w1r[k4];
            const f32x4 u = h0r[k4], w = h1r[k4];
            a0 += wv[0]*u[0] + wv[1]*u[1] + wv[2]*u[2] + wv[3]*u[3];
            a1 += wv[0]*w[0] + wv[1]*w[1] + wv[2]*w[2] + wv[3]*w[3];
        }
        const float bj = b1[j];
        mlp[(size_t)b0 * HID + j] = fmaxf(a0 + bj, 0.f);
        mlp[(size_t)(b0 + 32) * HID + j] = fmaxf(a1 + bj, 0.f);
    }
    __syncthreads();
    if (tid == 0) {
        __builtin_amdgcn_fence(__ATOMIC_RELEASE, "agent");
        __hip_atomic_fetch_add(doneM, 1u, __ATOMIC_RELAXED, __HIP_MEMORY_SCOPE_AGENT);
    }

    // out[b][o] = mlp[b] . W2[o] + b2[o]  (blocks 0..15, 8192 outputs)
    if (bid < 16) {
        if (tid == 0) {
            while (__hip_atomic_load(doneM, __ATOMIC_RELAXED,
                                     __HIP_MEMORY_SCOPE_AGENT) < (unsigned)NBLK)
                __builtin_amdgcn_s_sleep(2);
            __builtin_amdgcn_fence(__ATOMIC_ACQUIRE, "agent");
        }
        __syncthreads();
        const int g = bid * 512 + tid;
        const int b = g >> 7, o = g & 127;
        const f32x4* w2r = (const f32x4*)(W2 + (size_t)o * HID);
        const f32x4* mr  = (const f32x4*)(mlp + (size_t)b * HID);
        float a = 0.f;
        for (int k4 = 0; k4 < HID / 4; ++k4) {
            const f32x4 wv = w2r[k4], mv = mr[k4];
            a += wv[0]*mv[0] + wv[1]*mv[1] + wv[2]*mv[2] + wv[3]*mv[3];
        }
        out[b * 128 + o] = a + b2[o];
    }
}

extern "C" void kernel_launch(void* const* d_in, const int* in_sizes, int n_in,
                              void* d_out, int out_size, void* d_ws, size_t ws_size,
                              hipStream_t stream) {
    const float* x    = (const float*)d_in[0];
    const float* h0   = (const float*)d_in[1];
    const float* W_ih = (const float*)d_in[2];
    const float* b_ih = (const float*)d_in[3];
    const float* W_hh = (const float*)d_in[4];
    const float* b_hh = (const float*)d_in[5];
    const float* W1   = (const float*)d_in[6];
    const float* b1   = (const float*)d_in[7];
    const float* W2   = (const float*)d_in[8];
    const float* b2   = (const float*)d_in[9];
    float* out = (float*)d_out;
    unsigned short* wsu = (unsigned short*)d_ws;

    const int nprep = 1024 * KTOT + 65536;
    prep<<<nprep / 256, 256, 0, stream>>>(W_ih, W_hh, h0, wsu);

    void* args[] = {&x, &b_ih, &b_hh, &W1, &b1, &W2, &b2, &out, &wsu};
    hipLaunchCooperativeKernel(reinterpret_cast<void*>(rnn_mfma),
                               dim3(NBLK), dim3(512), args, 0, stream);
}

// Round 4
// 4846.165 us; speedup vs baseline: 8.1577x; 1.3948x over previous
//
#include <hip/hip_runtime.h>

#define HID   1024
#define NIN   128
#define BSZ   64
#define SLEN  512
#define KTOT  1152   // 1024 (W_hh) + 128 (W_ih)
#define NBLK  64
#define NOUT  128

typedef short          bf16x8 __attribute__((ext_vector_type(8)));
typedef unsigned short us8    __attribute__((ext_vector_type(8)));
typedef float          f32x4  __attribute__((ext_vector_type(4)));

__device__ __forceinline__ unsigned short rne_bf16(float f) {
    unsigned int u = __builtin_bit_cast(unsigned int, f);
    u += 0x7FFFu + ((u >> 16) & 1u);
    return (unsigned short)(u >> 16);
}
__device__ __forceinline__ float bf2f(unsigned short h) {
    unsigned int u = ((unsigned int)h) << 16;
    return __builtin_bit_cast(float, u);
}

// ws layout (ushort units):
//  Whi[1024*1152] | Wlo[1024*1152] | hA[131072] | hB[131072]
//  | hfp[64K floats] | mlp[64K floats] | sig[512*64+64 uints]
// h buffers interleaved: [b][k/8][8 hi | 8 lo]  (hi/lo of a fragment share a 32B line)
#define OFF_WLO 1179648
#define OFF_H0  2359296
#define OFF_H1  2490368
#define OFF_F32 2621440
#define OFF_SIG 2883584
#define SIG_N   (SLEN * 64 + 64)

__global__ void __launch_bounds__(256) prep(
    const float* __restrict__ W_ih, const float* __restrict__ W_hh,
    const float* __restrict__ h0, unsigned short* __restrict__ wsu)
{
    const int g = blockIdx.x * 256 + threadIdx.x;
    if (g < SIG_N) ((unsigned*)(wsu + OFF_SIG))[g] = 0u;
    if (g < 1024 * KTOT) {
        const int j = g / KTOT;
        const int k = g - j * KTOT;
        const float v = (k < HID) ? W_hh[j * HID + k] : W_ih[j * NIN + (k - HID)];
        const unsigned short hi = rne_bf16(v);
        wsu[g] = hi;
        wsu[OFF_WLO + g] = rne_bf16(v - bf2f(hi));
    } else if (g < 1024 * KTOT + 65536) {
        const int e = g - 1024 * KTOT;
        const int b = e >> 10, k = e & 1023;
        const float v = h0[e];
        const unsigned short hi = rne_bf16(v);
        const int base = OFF_H0 + b * 2048 + ((k >> 3) << 4) + (k & 7);
        wsu[base] = hi;
        wsu[base + 8] = rne_bf16(v - bf2f(hi));
    }
}

// 64 blocks = 32 j-tiles (32 wide) x 2 batch-halves; 512 threads = 8 waves:
// wave -> (kc = wave&3 K-quarter, m = wave>>2 M-subtile of 16 rows).
// W slice (hi+lo) XOR-swizzled in LDS; h ping-pong in ws; per-step publish via
// per-block sig slots (release store) + wave0 coalesced poll (no atomics).
__global__ void __launch_bounds__(512, 2) rnn_mfma(
    const float* __restrict__ x,
    const float* __restrict__ b_ih, const float* __restrict__ b_hh,
    const float* __restrict__ W1,   const float* __restrict__ b1,
    const float* __restrict__ W2,   const float* __restrict__ b2,
    float* __restrict__ out, unsigned short* __restrict__ wsu)
{
    const int tid  = threadIdx.x, bid = blockIdx.x;
    const int lane = tid & 63, wave = tid >> 6;
    const int lr = lane & 15, lg = lane >> 4;
    const int kc = wave & 3, m = wave >> 2;
    const int jb = bid >> 1, bh = bid & 1;
    const int j0 = jb * 32;

    const unsigned short* __restrict__ Whi = wsu;
    const unsigned short* __restrict__ Wlo = wsu + OFF_WLO;
    unsigned short* hA = wsu + OFF_H0;
    unsigned short* hB = wsu + OFF_H1;
    float* hfp = (float*)(wsu + OFF_F32);
    float* mlp = hfp + 65536;
    unsigned* sig = (unsigned*)(wsu + OFF_SIG);

    __shared__ unsigned short sW[2 * 32 * 1152];   // [hi/lo][row 0..31][k], XOR-swizzled
    __shared__ float red[2][32][33];

    // ---- stage W slice with T2 XOR swizzle: phys_c8 = c8 ^ (row&7) ----
    for (int e = tid; e < 32 * (KTOT / 8); e += 512) {
        const int row = e / (KTOT / 8), c8 = e - row * (KTOT / 8);
        const int pc8 = c8 ^ (row & 7);
        *(us8*)&sW[row * KTOT + pc8 * 8] =
            *(const us8*)(Whi + (size_t)(j0 + row) * KTOT + c8 * 8);
        *(us8*)&sW[32 * KTOT + row * KTOT + pc8 * 8] =
            *(const us8*)(Wlo + (size_t)(j0 + row) * KTOT + c8 * 8);
    }
    const int jl = tid & 31, b0 = tid >> 5;        // reducer: (b0 0..15, jl 0..31)
    const float bias = b_ih[j0 + jl] + b_hh[j0 + jl];
    __syncthreads();

    for (int t = 1; t <= SLEN; ++t) {
        const unsigned short* hcur = ((t - 1) & 1) ? hB : hA;
        unsigned short* hnxt = (t & 1) ? hB : hA;

        if (t > 1) {
            if (wave == 0) {
                const unsigned* s = sig + (size_t)(t - 2) * 64;
                while (!__all(__hip_atomic_load(s + lane, __ATOMIC_RELAXED,
                                                __HIP_MEMORY_SCOPE_AGENT) != 0u))
                    __builtin_amdgcn_s_sleep(1);
                __builtin_amdgcn_fence(__ATOMIC_ACQUIRE, "agent");
            }
            __syncthreads();
        }

        // ---- flat-batched A loads: 16 dwordx4 (h hi/lo pairs) + 2 x loads ----
        const int bglob = bh * 32 + m * 16 + lr;
        const unsigned short* hbp = hcur + bglob * 2048 + kc * 512 + lg * 16;
        bf16x8 ahh[9], ahl[9];
        #pragma unroll
        for (int ks = 0; ks < 8; ++ks) {
            ahh[ks] = *(const bf16x8*)(hbp + ks * 64);
            ahl[ks] = *(const bf16x8*)(hbp + ks * 64 + 8);
        }
        const float* xp = x + ((size_t)bglob * SLEN + (t - 1)) * NIN + kc * 32 + lg * 8;
        const f32x4 x0 = *(const f32x4*)xp;
        const f32x4 x1 = *(const f32x4*)(xp + 4);
        {
            bf16x8 xh, xl;
            #pragma unroll
            for (int e = 0; e < 4; ++e) {
                const unsigned short a = rne_bf16(x0[e]);
                xh[e] = (short)a; xl[e] = (short)rne_bf16(x0[e] - bf2f(a));
                const unsigned short b = rne_bf16(x1[e]);
                xh[4 + e] = (short)b; xl[4 + e] = (short)rne_bf16(x1[e] - bf2f(b));
            }
            ahh[8] = xh; ahl[8] = xl;
        }

        f32x4 acc0 = {0.f, 0.f, 0.f, 0.f}, acc1 = {0.f, 0.f, 0.f, 0.f};
        #pragma unroll
        for (int ks = 0; ks < 9; ++ks) {
            const int wc = (ks < 8) ? (kc * 256 + ks * 32 + lg * 8)
                                    : (1024 + kc * 32 + lg * 8);
            const int ci = (((wc >> 3) ^ (lr & 7)) << 3);
            const bf16x8 wh0 = *(const bf16x8*)&sW[lr * KTOT + ci];
            const bf16x8 wl0 = *(const bf16x8*)&sW[32 * KTOT + lr * KTOT + ci];
            const bf16x8 wh1 = *(const bf16x8*)&sW[(16 + lr) * KTOT + ci];
            const bf16x8 wl1 = *(const bf16x8*)&sW[32 * KTOT + (16 + lr) * KTOT + ci];
            acc0 = __builtin_amdgcn_mfma_f32_16x16x32_bf16(ahh[ks], wh0, acc0, 0, 0, 0);
            acc0 = __builtin_amdgcn_mfma_f32_16x16x32_bf16(ahh[ks], wl0, acc0, 0, 0, 0);
            acc0 = __builtin_amdgcn_mfma_f32_16x16x32_bf16(ahl[ks], wh0, acc0, 0, 0, 0);
            acc1 = __builtin_amdgcn_mfma_f32_16x16x32_bf16(ahh[ks], wh1, acc1, 0, 0, 0);
            acc1 = __builtin_amdgcn_mfma_f32_16x16x32_bf16(ahh[ks], wl1, acc1, 0, 0, 0);
            acc1 = __builtin_amdgcn_mfma_f32_16x16x32_bf16(ahl[ks], wh1, acc1, 0, 0, 0);
        }

        // ---- 2-phase K-reduce in LDS (fits 160KB with 147KB W slice) ----
        if (kc < 2) {
            #pragma unroll
            for (int r = 0; r < 4; ++r) {
                red[kc][m * 16 + lg * 4 + r][lr]      = acc0[r];
                red[kc][m * 16 + lg * 4 + r][16 + lr] = acc1[r];
            }
        }
        __syncthreads();
        const float part0 = red[0][b0][jl] + red[1][b0][jl];
        const float part1 = red[0][b0 + 16][jl] + red[1][b0 + 16][jl];
        __syncthreads();
        if (kc >= 2) {
            #pragma unroll
            for (int r = 0; r < 4; ++r) {
                red[kc - 2][m * 16 + lg * 4 + r][lr]      = acc0[r];
                red[kc - 2][m * 16 + lg * 4 + r][16 + lr] = acc1[r];
            }
        }
        __syncthreads();

        #pragma unroll
        for (int half = 0; half < 2; ++half) {
            const int bl = b0 + half * 16;
            const float p = half ? part1 : part0;
            const float s = p + red[0][bl][jl] + red[1][bl][jl] + bias;
            const float v = tanhf(s);
            const int bg = bh * 32 + bl;
            const int jg = j0 + jl;
            const unsigned short hb16 = rne_bf16(v);
            const int ha = bg * 2048 + ((jg >> 3) << 4) + (jg & 7);
            hnxt[ha] = hb16;
            hnxt[ha + 8] = rne_bf16(v - bf2f(hb16));
            if (t == SLEN) {
                hfp[bg * HID + jg] = v;
                out[BSZ * NOUT + bg * HID + jg] = v;
            }
        }
        __syncthreads();   // all h stores drained (vmcnt0) before signal
        if (tid == 0)
            __hip_atomic_store(sig + (size_t)(t - 1) * 64 + bid, 1u,
                               __ATOMIC_RELEASE, __HIP_MEMORY_SCOPE_AGENT);
    }

    // ---- head: wait for full h_last ----
    if (wave == 0) {
        const unsigned* s = sig + (size_t)(SLEN - 1) * 64;
        while (!__all(__hip_atomic_load(s + lane, __ATOMIC_RELAXED,
                                        __HIP_MEMORY_SCOPE_AGENT) != 0u))
            __builtin_amdgcn_s_sleep(1);
        __builtin_amdgcn_fence(__ATOMIC_ACQUIRE, "agent");
    }
    __syncthreads();

    // mlp[b][j] = relu(h_last[b] . W1[j] + b1[j]); block: its 32 j x its 32 b
    {
        const int jg = j0 + jl;
        const f32x4* w1r = (const f32x4*)(W1 + (size_t)jg * HID);
        const int bA = bh * 32 + b0, bB = bA + 16;
        const f32x4* hA4 = (const f32x4*)(hfp + (size_t)bA * HID);
        const f32x4* hB4 = (const f32x4*)(hfp + (size_t)bB * HID);
        float a0 = 0.f, a1 = 0.f;
        for (int k4 = 0; k4 < HID / 4; ++k4) {
            const f32x4 wv = w1r[k4];
            const f32x4 u = hA4[k4], w = hB4[k4];
            a0 += wv[0]*u[0] + wv[1]*u[1] + wv[2]*u[2] + wv[3]*u[3];
            a1 += wv[0]*w[0] + wv[1]*w[1] + wv[2]*w[2] + wv[3]*w[3];
        }
        const float bj = b1[jg];
        mlp[(size_t)bA * HID + jg] = fmaxf(a0 + bj, 0.f);
        mlp[(size_t)bB * HID + jg] = fmaxf(a1 + bj, 0.f);
    }
    __syncthreads();
    if (tid == 0)
        __hip_atomic_store(sig + (size_t)SLEN * 64 + bid, 1u,
                           __ATOMIC_RELEASE, __HIP_MEMORY_SCOPE_AGENT);

    // out[b][o] = mlp[b] . W2[o] + b2[o]  (blocks 0..15, 8192 outputs)
    if (bid < 16) {
        if (wave == 0) {
            const unsigned* s = sig + (size_t)SLEN * 64;
            while (!__all(__hip_atomic_load(s + lane, __ATOMIC_RELAXED,
                                            __HIP_MEMORY_SCOPE_AGENT) != 0u))
                __builtin_amdgcn_s_sleep(1);
            __builtin_amdgcn_fence(__ATOMIC_ACQUIRE, "agent");
        }
        __syncthreads();
        const int g = bid * 512 + tid;
        const int b = g >> 7, o = g & 127;
        const f32x4* w2r = (const f32x4*)(W2 + (size_t)o * HID);
        const f32x4* mr  = (const f32x4*)(mlp + (size_t)b * HID);
        float a = 0.f;
        for (int k4 = 0; k4 < HID / 4; ++k4) {
            const f32x4 wv = w2r[k4], mv = mr[k4];
            a += wv[0]*mv[0] + wv[1]*mv[1] + wv[2]*mv[2] + wv[3]*mv[3];
        }
        out[b * NOUT + o] = a + b2[o];
    }
}

extern "C" void kernel_launch(void* const* d_in, const int* in_sizes, int n_in,
                              void* d_out, int out_size, void* d_ws, size_t ws_size,
                              hipStream_t stream) {
    const float* x    = (const float*)d_in[0];
    const float* h0   = (const float*)d_in[1];
    const float* W_ih = (const float*)d_in[2];
    const float* b_ih = (const float*)d_in[3];
    const float* W_hh = (const float*)d_in[4];
    const float* b_hh = (const float*)d_in[5];
    const float* W1   = (const float*)d_in[6];
    const float* b1   = (const float*)d_in[7];
    const float* W2   = (const float*)d_in[8];
    const float* b2   = (const float*)d_in[9];
    float* out = (float*)d_out;
    unsigned short* wsu = (unsigned short*)d_ws;

    const int nprep = 1024 * KTOT + 65536;   // covers SIG_N zeroing too
    prep<<<(nprep + 255) / 256, 256, 0, stream>>>(W_ih, W_hh, h0, wsu);

    void* args[] = {&x, &b_ih, &b_hh, &W1, &b1, &W2, &b2, &out, &wsu};
    hipLaunchCooperativeKernel(reinterpret_cast<void*>(rnn_mfma),
                               dim3(NBLK), dim3(512), args, 0, stream);
}